// Round 6
// baseline (251.073 us; speedup 1.0000x reference)
//
#include <hip/hip_runtime.h>

// Problem constants (B=8192, S=32, N=128, K=64, M=3)
#define BATCH 8192
#define EPSF  1e-9f
#define C_LD  68              // |C| LDS tile leading dim (conflict-free col writes)

typedef float floatx16 __attribute__((ext_vector_type(16)));
typedef short shortx8  __attribute__((ext_vector_type(8)));

// insert v into descending top-4
__device__ __forceinline__ void ins4(float v, float& t0, float& t1, float& t2, float& t3) {
    float m;
    m = fminf(t0, v); t0 = fmaxf(t0, v); v = m;
    m = fminf(t1, v); t1 = fmaxf(t1, v); v = m;
    m = fminf(t2, v); t2 = fmaxf(t2, v); v = m;
    t3 = fmaxf(t3, v);
}

// merge a second descending top-4 (b0..b3) into t0..t3 (bitonic)
__device__ __forceinline__ void merge4(float& t0, float& t1, float& t2, float& t3,
                                       float b0, float b1, float b2, float b3) {
    float c0 = fmaxf(t0, b3);
    float c1 = fmaxf(t1, b2);
    float c2 = fmaxf(t2, b1);
    float c3 = fmaxf(t3, b0);
    float d0 = fmaxf(c0, c2), d2 = fminf(c0, c2);
    float d1 = fmaxf(c1, c3), d3 = fminf(c1, c3);
    t0 = fmaxf(d0, d1); t1 = fminf(d0, d1);
    t2 = fmaxf(d2, d3); t3 = fminf(d2, d3);
}

// ONE WAVE PER BLOCK, one batch per wave (8192 blocks x 64 threads).
// C = x(32x64) @ P(64x64) via split-bf16 MFMA (hi/lo truncation split,
// C = hi*hi + hi*lo + lo*hi, rel err ~1e-5). Fragments (32x32x16_bf16):
//   A[m=lane&31][k=(lane>>5)*8+16*ks+j], B likewise, C/D col=lane&31,
//   row=(reg&3)+8*(reg>>2)+4*(lane>>5).
// MLP strategy: ALL 72 vmem loads (x + both P column-tiles) are issued into
// separate register buffers before any conversion/compute — ~18 KB in flight
// per wave, so HBM/L3 latency is covered by a handful of waves. Single-wave
// blocks avoid convoying and need no barriers at all.
__global__ __launch_bounds__(64) void avl_main(
    const float* __restrict__ y_pred,
    const float* __restrict__ y_true,
    const float* __restrict__ P,   // [B][64][64]
    const float* __restrict__ X,   // [B][32][64]
    float* __restrict__ partial)   // [BATCH][2]: {violation, logmse}
{
    __shared__ float Cw[32 * C_LD];   // 8704 B, wave-private

    const int lane = threadIdx.x;
    const int kg   = lane >> 5;   // K-half: k = kg*8 + 16*ks + j
    const int m    = lane & 31;   // A/C row-col index
    const int b    = blockIdx.x;

    // ---- issue ALL loads first (x, then P tile0, then P tile1) ----
    const float* xg = X + (size_t)b * 2048 + m * 64 + kg * 8;
    float4 xa[4], xb[4];
#pragma unroll
    for (int ks = 0; ks < 4; ++ks) {
        xa[ks] = *(const float4*)(xg + ks * 16);
        xb[ks] = *(const float4*)(xg + ks * 16 + 4);
    }

    const float* pg = P + (size_t)b * 4096 + (kg * 8) * 64 + m;
    float pv0[32], pv1[32];
#pragma unroll
    for (int ks = 0; ks < 4; ++ks)
#pragma unroll
        for (int i = 0; i < 8; ++i)
            pv0[ks * 8 + i] = pg[(ks * 16 + i) * 64];
#pragma unroll
    for (int ks = 0; ks < 4; ++ks)
#pragma unroll
        for (int i = 0; i < 8; ++i)
            pv1[ks * 8 + i] = pg[(ks * 16 + i) * 64 + 32];

    // ---- convert x to hi/lo bf16 A-frags; fold |x| into local top-4 ----
    float t0 = -1.f, t1 = -1.f, t2 = -1.f, t3 = -1.f;
    shortx8 ahi[4], alo[4];
#pragma unroll
    for (int ks = 0; ks < 4; ++ks) {
        const float v[8] = { xa[ks].x, xa[ks].y, xa[ks].z, xa[ks].w,
                             xb[ks].x, xb[ks].y, xb[ks].z, xb[ks].w };
#pragma unroll
        for (int i = 0; i < 8; ++i) {
            const float x = v[i];
            const unsigned bits = __float_as_uint(x);
            ahi[ks][i] = (short)(bits >> 16);
            const float hif = __uint_as_float(bits & 0xFFFF0000u);
            alo[ks][i] = (short)(__float_as_uint(x - hif) >> 16);
            ins4(fabsf(x), t0, t1, t2, t3);
        }
    }

    // ---- per-tile: convert P, 12 MFMAs, |C| -> LDS row-major ----
#pragma unroll
    for (int tile = 0; tile < 2; ++tile) {
        const float* pv = tile ? pv1 : pv0;

        shortx8 bhi[4], blo[4];
#pragma unroll
        for (int ks = 0; ks < 4; ++ks)
#pragma unroll
            for (int i = 0; i < 8; ++i) {
                const float p = pv[ks * 8 + i];
                const unsigned bits = __float_as_uint(p);
                bhi[ks][i] = (short)(bits >> 16);
                const float hif = __uint_as_float(bits & 0xFFFF0000u);
                blo[ks][i] = (short)(__float_as_uint(p - hif) >> 16);
            }

        floatx16 acc;
#pragma unroll
        for (int r = 0; r < 16; ++r) acc[r] = 0.f;
#pragma unroll
        for (int ks = 0; ks < 4; ++ks) {
            acc = __builtin_amdgcn_mfma_f32_32x32x16_bf16(alo[ks], bhi[ks], acc, 0, 0, 0);
            acc = __builtin_amdgcn_mfma_f32_32x32x16_bf16(ahi[ks], blo[ks], acc, 0, 0, 0);
            acc = __builtin_amdgcn_mfma_f32_32x32x16_bf16(ahi[ks], bhi[ks], acc, 0, 0, 0);
        }

#pragma unroll
        for (int reg = 0; reg < 16; ++reg) {
            const int row = (reg & 3) + 8 * (reg >> 2) + 4 * kg;
            Cw[row * C_LD + tile * 32 + m] = fabsf(acc[reg]);
        }
    }

    // ---- top-4 of |[x_row | C_row]|: lane owns row m, C-cols kg*32..+31 ----
    // (wave-private LDS: compiler inserts lgkmcnt wait, no barrier needed)
    const float* cr = Cw + m * C_LD + kg * 32;
#pragma unroll
    for (int t = 0; t < 8; ++t) {
        const float4 c = *(const float4*)(cr + 4 * t);
        ins4(c.x, t0, t1, t2, t3);
        ins4(c.y, t0, t1, t2, t3);
        ins4(c.z, t0, t1, t2, t3);
        ins4(c.w, t0, t1, t2, t3);
    }

    // merge complementary half (lane L and L^32 cover disjoint value sets)
    {
        const float b0 = __shfl_xor(t0, 32, 64);
        const float b1 = __shfl_xor(t1, 32, 64);
        const float b2 = __shfl_xor(t2, 32, 64);
        const float b3 = __shfl_xor(t3, 32, 64);
        merge4(t0, t1, t2, t3, b0, b1, b2, b3);
    }

    float h = t0 / (t3 + EPSF);
#pragma unroll
    for (int msk = 1; msk <= 16; msk <<= 1)
        h = fmaxf(h, __shfl_xor(h, msk, 64));

    if (lane == 0) {
        const float yp = y_pred[b];
        partial[b * 2 + 0] = fmaxf(h - yp, 0.f);
        const float lp = log2f(fmaxf(yp, EPSF));
        const float lt = log2f(fmaxf(y_true[b], EPSF));
        const float d = lt - lp;
        partial[b * 2 + 1] = d * d;
    }
}

__global__ __launch_bounds__(256) void avl_final(
    const float* __restrict__ partial, float* __restrict__ out)
{
    const int tid  = threadIdx.x;
    const int wave = tid >> 6;
    const int lane = tid & 63;
    float s0 = 0.f, s1 = 0.f;
    for (int i = tid; i < BATCH; i += 256) {
        s0 += partial[2 * i + 0];
        s1 += partial[2 * i + 1];
    }
#pragma unroll
    for (int msk = 1; msk <= 32; msk <<= 1) {
        s0 += __shfl_xor(s0, msk, 64);
        s1 += __shfl_xor(s1, msk, 64);
    }
    __shared__ float r0[4], r1[4];
    if (lane == 0) { r0[wave] = s0; r1[wave] = s1; }
    __syncthreads();
    if (tid == 0) {
        const float vi = (r0[0] + r0[1] + r0[2] + r0[3]) * (1.0f / (float)BATCH);
        const float lm = (r1[0] + r1[1] + r1[2] + r1[3]) * (1.0f / (float)BATCH);
        out[0] = lm + 0.5f * vi;   // total_loss
        out[1] = lm;               // loss_logmse
        out[2] = vi;               // loss_violation
    }
}

extern "C" void kernel_launch(void* const* d_in, const int* in_sizes, int n_in,
                              void* d_out, int out_size, void* d_ws, size_t ws_size,
                              hipStream_t stream)
{
    const float* y_pred = (const float*)d_in[0];
    const float* y_true = (const float*)d_in[1];
    const float* P      = (const float*)d_in[2];
    const float* X      = (const float*)d_in[3];

    float* partial = (float*)d_ws;   // BATCH*2 floats = 64 KB
    avl_main<<<BATCH, 64, 0, stream>>>(y_pred, y_true, P, X, partial);
    avl_final<<<1, 256, 0, stream>>>(partial, (float*)d_out);
}